// Round 1
// baseline (1074.331 us; speedup 1.0000x reference)
//
#include <hip/hip_runtime.h>

#define NN 50000      // nodes
#define NE 800000     // edges
#define DD 64         // feature dim
#define ED 16         // edge attr dim
#define NG 5000       // graphs

// ---------------------------------------------------------------------------
// Per-node projections for CGConv:
//   Af[n][d] = sum_k h[n][k]*Wf[k][d]        + bf[d]   (dst / x_i part, rows 0..63)
//   Bf[n][d] = sum_k h[n][k]*Wf[64+k][d]               (src / x_j part, rows 64..127)
//   As, Bs likewise with Ws/sb.
// Block = 256 threads = 4 nodes x 64 dims. Weights read through L1 (tiny, hot).
__global__ __launch_bounds__(256) void node_transform(
    const float* __restrict__ h,
    const float* __restrict__ Wf, const float* __restrict__ bf,
    const float* __restrict__ Ws, const float* __restrict__ sb,
    float* __restrict__ Af, float* __restrict__ Bf,
    float* __restrict__ As, float* __restrict__ Bs) {
  __shared__ float hrow[4][DD];
  int tid = threadIdx.x, g = tid >> 6, d = tid & 63;
  int n = blockIdx.x * 4 + g;               // NN % 4 == 0, no tail
  hrow[g][d] = h[(size_t)n * DD + d];
  __syncthreads();
  float af = bf[d], bfv = 0.f, as = sb[d], bs = 0.f;
#pragma unroll
  for (int k = 0; k < DD; ++k) {
    float hv = hrow[g][k];
    af  = fmaf(hv, Wf[k * DD + d], af);
    bfv = fmaf(hv, Wf[(DD + k) * DD + d], bfv);
    as  = fmaf(hv, Ws[k * DD + d], as);
    bs  = fmaf(hv, Ws[(DD + k) * DD + d], bs);
  }
  size_t o = (size_t)n * DD + d;
  Af[o] = af; Bf[o] = bfv; As[o] = as; Bs[o] = bs;
}

// ---------------------------------------------------------------------------
// Per-edge: gate = sigmoid(Af[dst]+Bf[src]+ea@WfB), val = softplus(As[dst]+Bs[src]+ea@WsB)
// atomicAdd(out[dst], gate*val).  Block = 256 = 4 edges x 64 dims.
__global__ __launch_bounds__(256) void edge_kernel(
    const int* __restrict__ ei, const float* __restrict__ ea,
    const float* __restrict__ WfB, const float* __restrict__ WsB,  // 16x64 slices
    const float* __restrict__ Af, const float* __restrict__ Bf,
    const float* __restrict__ As, const float* __restrict__ Bs,
    float* __restrict__ out) {
  __shared__ float sWf[ED * DD], sWs[ED * DD];
  __shared__ float sEA[4][ED];
  int tid = threadIdx.x;
  for (int i = tid; i < ED * DD; i += 256) { sWf[i] = WfB[i]; sWs[i] = WsB[i]; }
  int g = tid >> 6, d = tid & 63;
  int e = blockIdx.x * 4 + g;               // NE % 4 == 0, no tail
  if (d < ED) sEA[g][d] = ea[(size_t)e * ED + d];
  __syncthreads();

  int src = ei[e];
  int dst = ei[NE + e];
  float cf = 0.f, cs = 0.f;
#pragma unroll
  for (int k = 0; k < ED; ++k) {
    float z = sEA[g][k];
    cf = fmaf(z, sWf[k * DD + d], cf);
    cs = fmaf(z, sWs[k * DD + d], cs);
  }
  size_t od = (size_t)dst * DD + d;
  size_t os = (size_t)src * DD + d;
  float gl = Af[od] + Bf[os] + cf;
  float sl = As[od] + Bs[os] + cs;
  float sig = 1.f / (1.f + expf(-gl));
  float sp  = fmaxf(sl, 0.f) + log1pf(expf(-fabsf(sl)));   // stable softplus
  atomicAdd(&out[od], sig * sp);
}

// ---------------------------------------------------------------------------
// BN stats: per-channel sum and sumsq. Thread's channel fixed = tid&63.
__global__ __launch_bounds__(256) void bn_stats(const float* __restrict__ h,
                                                float* __restrict__ stats) {
  int tid = threadIdx.x, d = tid & 63;
  int row0 = blockIdx.x * 4 + (tid >> 6);
  int stride = gridDim.x * 4;
  float s = 0.f, ss = 0.f;
  for (int r = row0; r < NN; r += stride) {
    float v = h[(size_t)r * DD + d];
    s += v; ss += v * v;
  }
  __shared__ float sb[256], ssb[256];
  sb[tid] = s; ssb[tid] = ss;
  __syncthreads();
  if (tid < 128) { sb[tid] += sb[tid + 128]; ssb[tid] += ssb[tid + 128]; }
  __syncthreads();
  if (tid < 64) {
    atomicAdd(&stats[d],      sb[tid] + sb[tid + 64]);
    atomicAdd(&stats[64 + d], ssb[tid] + ssb[tid + 64]);
  }
}

__global__ void bn_finalize(float* __restrict__ stats,
                            const float* __restrict__ gamma,
                            const float* __restrict__ beta) {
  int d = threadIdx.x;  // 64 threads
  const float invN = 1.f / (float)NN;
  float mu  = stats[d] * invN;
  float var = stats[64 + d] * invN - mu * mu;
  float rs  = rsqrtf(var + 1e-5f);
  float sc  = rs * gamma[d];
  stats[128 + d] = sc;
  stats[192 + d] = beta[d] - mu * sc;
}

__global__ __launch_bounds__(256) void bn_apply(float* __restrict__ h,
                                                const float* __restrict__ stats) {
  const int n4 = NN * DD / 4;  // 800000 float4s
  const float4* sc4 = (const float4*)(stats + 128);
  const float4* sh4 = (const float4*)(stats + 192);
  for (int i = blockIdx.x * 256 + threadIdx.x; i < n4; i += gridDim.x * 256) {
    float4 v = ((float4*)h)[i];
    int c = i & 15;           // 16 float4 groups per 64-channel row
    float4 sc = sc4[c], sh = sh4[c];
    v.x = fmaf(v.x, sc.x, sh.x);
    v.y = fmaf(v.y, sc.y, sh.y);
    v.z = fmaf(v.z, sc.z, sh.z);
    v.w = fmaf(v.w, sc.w, sh.w);
    ((float4*)h)[i] = v;
  }
}

// ---------------------------------------------------------------------------
__global__ __launch_bounds__(256) void pool_kernel(const float* __restrict__ h,
                                                   const int* __restrict__ batch,
                                                   float* __restrict__ psum,
                                                   float* __restrict__ pcnt) {
  int tid = threadIdx.x, g = tid >> 6, d = tid & 63;
  int n = blockIdx.x * 4 + g;               // NN % 4 == 0
  int b = batch[n];
  atomicAdd(&psum[(size_t)b * DD + d], h[(size_t)n * DD + d]);
  if (d == 0) atomicAdd(&pcnt[b], 1.0f);
}

__global__ __launch_bounds__(256) void head_kernel(
    const float* __restrict__ psum, const float* __restrict__ pcnt,
    const float* __restrict__ pw1, const float* __restrict__ pb1,
    const float* __restrict__ pw2, const float* __restrict__ pb2,
    float* __restrict__ out) {
  __shared__ float row[4][DD], y1[4][DD];
  int tid = threadIdx.x, g = tid >> 6, d = tid & 63;
  int q = blockIdx.x * 4 + g;               // NG % 4 == 0
  float c = fmaxf(pcnt[q], 1.0f);
  row[g][d] = psum[(size_t)q * DD + d] / c;
  __syncthreads();
  float acc = pb1[d];
#pragma unroll
  for (int k = 0; k < DD; ++k) acc = fmaf(row[g][k], pw1[k * DD + d], acc);
  acc = acc > 0.f ? acc : 0.01f * acc;      // leaky relu
  y1[g][d] = acc;
  __syncthreads();
  float o = pb2[d];
#pragma unroll
  for (int k = 0; k < DD; ++k) o = fmaf(y1[g][k], pw2[k * DD + d], o);
  out[(size_t)q * DD + d] = o;
}

// ---------------------------------------------------------------------------
extern "C" void kernel_launch(void* const* d_in, const int* in_sizes, int n_in,
                              void* d_out, int out_size, void* d_ws, size_t ws_size,
                              hipStream_t stream) {
  const float* x     = (const float*)d_in[0];
  const int*   ei    = (const int*)d_in[1];
  const float* ea    = (const float*)d_in[2];
  const int*   batch = (const int*)d_in[3];
  const float* fw0 = (const float*)d_in[4],  *fb0 = (const float*)d_in[5];
  const float* sw0 = (const float*)d_in[6],  *sb0 = (const float*)d_in[7];
  const float* bng0= (const float*)d_in[8],  *bnb0= (const float*)d_in[9];
  const float* fw1 = (const float*)d_in[10], *fb1 = (const float*)d_in[11];
  const float* sw1 = (const float*)d_in[12], *sb1 = (const float*)d_in[13];
  const float* bng1= (const float*)d_in[14], *bnb1= (const float*)d_in[15];
  const float* pw1 = (const float*)d_in[16], *pb1 = (const float*)d_in[17];
  const float* pw2 = (const float*)d_in[18], *pb2 = (const float*)d_in[19];

  const size_t NND = (size_t)NN * DD;
  float* ws = (float*)d_ws;
  float* Af = ws;
  float* Bf = Af + NND;
  float* As = Bf + NND;
  float* Bs = As + NND;
  float* h1 = Bs + NND;
  float* h2 = h1 + NND;
  float* stats0 = h2 + NND;          // 256 floats
  float* stats1 = stats0 + 256;      // 256 floats
  float* psum   = stats1 + 256;      // NG*DD
  float* pcnt   = psum + (size_t)NG * DD;  // NG

  // zero stats + pooling accumulators (contiguous region)
  hipMemsetAsync(stats0, 0, (512 + (size_t)NG * DD + NG) * sizeof(float), stream);

  // ---- layer 0 ----
  node_transform<<<NN / 4, 256, 0, stream>>>(x, fw0, fb0, sw0, sb0, Af, Bf, As, Bs);
  hipMemcpyAsync(h1, x, NND * sizeof(float), hipMemcpyDeviceToDevice, stream);
  edge_kernel<<<NE / 4, 256, 0, stream>>>(ei, ea, fw0 + 128 * DD, sw0 + 128 * DD,
                                          Af, Bf, As, Bs, h1);
  bn_stats<<<256, 256, 0, stream>>>(h1, stats0);
  bn_finalize<<<1, 64, 0, stream>>>(stats0, bng0, bnb0);
  bn_apply<<<1024, 256, 0, stream>>>(h1, stats0);

  // ---- layer 1 ----
  node_transform<<<NN / 4, 256, 0, stream>>>(h1, fw1, fb1, sw1, sb1, Af, Bf, As, Bs);
  hipMemcpyAsync(h2, h1, NND * sizeof(float), hipMemcpyDeviceToDevice, stream);
  edge_kernel<<<NE / 4, 256, 0, stream>>>(ei, ea, fw1 + 128 * DD, sw1 + 128 * DD,
                                          Af, Bf, As, Bs, h2);
  bn_stats<<<256, 256, 0, stream>>>(h2, stats1);
  bn_finalize<<<1, 64, 0, stream>>>(stats1, bng1, bnb1);
  bn_apply<<<1024, 256, 0, stream>>>(h2, stats1);

  // ---- pool + head ----
  pool_kernel<<<NN / 4, 256, 0, stream>>>(h2, batch, psum, pcnt);
  head_kernel<<<NG / 4, 256, 0, stream>>>(psum, pcnt, pw1, pb1, pw2, pb2, (float*)d_out);
}

// Round 2
// 964.597 us; speedup vs baseline: 1.1138x; 1.1138x over previous
//
#include <hip/hip_runtime.h>

#define NN 50000      // nodes
#define NE 800000     // edges
#define DD 64         // feature dim
#define ED 16         // edge attr dim
#define NG 5000       // graphs

// ---------------------------------------------------------------------------
// Interleave weights: Wd[k][d]={Wf[k][d],Ws[k][d]} (dst rows 0..63),
// Wsc[k][d] (src rows 64..127), We[k][d] (edge rows 128..143).
__global__ __launch_bounds__(256) void prep_weights(
    const float* __restrict__ fw, const float* __restrict__ sw,
    float2* __restrict__ Wd, float2* __restrict__ Wsc, float2* __restrict__ We) {
  int i = blockIdx.x * 256 + threadIdx.x;   // over 144*64
  if (i >= 144 * 64) return;
  int k = i >> 6, d = i & 63;
  float2 v = make_float2(fw[i], sw[i]);
  if (k < 64)       Wd[k * DD + d] = v;
  else if (k < 128) Wsc[(k - 64) * DD + d] = v;
  else              We[(k - 128) * DD + d] = v;
}

// ---------------------------------------------------------------------------
// Node transform: Dst[n][d]={Af,As}, Src[n][d]={Bf,Bs}; also writes hcopy
// (residual base). BN=1: applies BN affine (from stats[128..]) to input first.
template <int BN>
__global__ __launch_bounds__(256) void node_transform(
    const float* __restrict__ hin, const float* __restrict__ stats,
    const float2* __restrict__ Wd, const float2* __restrict__ Wsc,
    const float* __restrict__ bf, const float* __restrict__ sbv,
    float2* __restrict__ Dst, float2* __restrict__ Src,
    float* __restrict__ hcopy) {
  __shared__ float hrow[4][DD];
  int tid = threadIdx.x, g = tid >> 6, d = tid & 63;
  int n = blockIdx.x * 4 + g;               // NN % 4 == 0
  float v = hin[(size_t)n * DD + d];
  if (BN) v = fmaf(v, stats[128 + d], stats[192 + d]);
  hrow[g][d] = v;
  hcopy[(size_t)n * DD + d] = v;
  __syncthreads();
  float2 ad = make_float2(bf[d], sbv[d]);
  float2 as = make_float2(0.f, 0.f);
#pragma unroll
  for (int k = 0; k < DD; ++k) {
    float hv = hrow[g][k];
    float2 wd = Wd[k * DD + d];
    ad.x = fmaf(hv, wd.x, ad.x); ad.y = fmaf(hv, wd.y, ad.y);
    float2 ws = Wsc[k * DD + d];
    as.x = fmaf(hv, ws.x, as.x); as.y = fmaf(hv, ws.y, as.y);
  }
  Dst[(size_t)n * DD + d] = ad;
  Src[(size_t)n * DD + d] = as;
}

// ---------------------------------------------------------------------------
// Edge kernel: gl = Dst[dst].x + Src[src].x + ea@We.x ; sl likewise (.y)
// out[dst] += sigmoid(gl)*softplus(sl). Block stages We once, loops 64 edges.
__global__ __launch_bounds__(256) void edge_kernel(
    const int* __restrict__ ei, const float4* __restrict__ ea4,
    const float2* __restrict__ We,
    const float2* __restrict__ Dst, const float2* __restrict__ Src,
    float* __restrict__ out) {
  __shared__ float2 sW[ED * DD];            // 8 KB
  int tid = threadIdx.x;
#pragma unroll
  for (int i = tid; i < ED * DD; i += 256) sW[i] = We[i];
  __syncthreads();
  int g = tid >> 6, d = tid & 63;
  int e = blockIdx.x * 64 + g;
#pragma unroll 2
  for (int it = 0; it < 16; ++it, e += 4) {
    int srcn = ei[e];
    int dstn = ei[NE + e];
    float4 q0 = ea4[(size_t)e * 4 + 0];
    float4 q1 = ea4[(size_t)e * 4 + 1];
    float4 q2 = ea4[(size_t)e * 4 + 2];
    float4 q3 = ea4[(size_t)e * 4 + 3];
    float z[16] = {q0.x, q0.y, q0.z, q0.w, q1.x, q1.y, q1.z, q1.w,
                   q2.x, q2.y, q2.z, q2.w, q3.x, q3.y, q3.z, q3.w};
    float cf = 0.f, cs = 0.f;
#pragma unroll
    for (int k = 0; k < ED; ++k) {
      float2 w = sW[k * DD + d];
      cf = fmaf(z[k], w.x, cf);
      cs = fmaf(z[k], w.y, cs);
    }
    float2 a = Dst[(size_t)dstn * DD + d];
    float2 b = Src[(size_t)srcn * DD + d];
    float gl = a.x + b.x + cf;
    float sl = a.y + b.y + cs;
    float sig = __builtin_amdgcn_rcpf(1.f + __expf(-gl));     // fast sigmoid
    float sp  = fmaxf(sl, 0.f) + __logf(1.f + __expf(-fabsf(sl))); // softplus
    atomicAdd(&out[(size_t)dstn * DD + d], sig * sp);
  }
}

// ---------------------------------------------------------------------------
// BN stats via float4: thread owns 4 channels, 16 threads span a row.
__global__ __launch_bounds__(256) void bn_stats(const float* __restrict__ h,
                                                float* __restrict__ stats) {
  int tid = threadIdx.x;
  int c = (tid & 15) * 4;
  int r0 = blockIdx.x * 16 + (tid >> 4);
  float4 s = make_float4(0, 0, 0, 0), ss = make_float4(0, 0, 0, 0);
  for (int r = r0; r < NN; r += gridDim.x * 16) {
    float4 v = *(const float4*)(h + (size_t)r * DD + c);
    s.x += v.x; s.y += v.y; s.z += v.z; s.w += v.w;
    ss.x += v.x * v.x; ss.y += v.y * v.y; ss.z += v.z * v.z; ss.w += v.w * v.w;
  }
  __shared__ float4 sm[256], sm2[256];
  sm[tid] = s; sm2[tid] = ss;
  __syncthreads();
  for (int str = 128; str >= 16; str >>= 1) {
    if (tid < str) {
      sm[tid].x += sm[tid + str].x; sm[tid].y += sm[tid + str].y;
      sm[tid].z += sm[tid + str].z; sm[tid].w += sm[tid + str].w;
      sm2[tid].x += sm2[tid + str].x; sm2[tid].y += sm2[tid + str].y;
      sm2[tid].z += sm2[tid + str].z; sm2[tid].w += sm2[tid + str].w;
    }
    __syncthreads();
  }
  if (tid < 16) {
    int cc = tid * 4;
    atomicAdd(&stats[cc + 0], sm[tid].x); atomicAdd(&stats[cc + 1], sm[tid].y);
    atomicAdd(&stats[cc + 2], sm[tid].z); atomicAdd(&stats[cc + 3], sm[tid].w);
    atomicAdd(&stats[64 + cc + 0], sm2[tid].x); atomicAdd(&stats[64 + cc + 1], sm2[tid].y);
    atomicAdd(&stats[64 + cc + 2], sm2[tid].z); atomicAdd(&stats[64 + cc + 3], sm2[tid].w);
  }
}

__global__ void bn_finalize(float* __restrict__ stats,
                            const float* __restrict__ gamma,
                            const float* __restrict__ beta) {
  int d = threadIdx.x;  // 64 threads
  const float invN = 1.f / (float)NN;
  float mu  = stats[d] * invN;
  float var = stats[64 + d] * invN - mu * mu;
  float rs  = rsqrtf(var + 1e-5f);
  float sc  = rs * gamma[d];
  stats[128 + d] = sc;
  stats[192 + d] = beta[d] - mu * sc;
}

// ---------------------------------------------------------------------------
// Pool with fused BN1 affine; exploits sorted batch via run-length accumulate.
__global__ __launch_bounds__(256) void pool_bn(
    const float* __restrict__ h, const int* __restrict__ batch,
    const float* __restrict__ stats,
    float* __restrict__ psum, float* __restrict__ pcnt) {
  int tid = threadIdx.x, g = tid >> 6, d = tid & 63;
  float sc = stats[128 + d], sh = stats[192 + d];
  int n0 = (blockIdx.x * 4 + g) * 32;
  if (n0 >= NN) return;
  int nend = n0 + 32; if (nend > NN) nend = NN;
  int bprev = batch[n0];
  float acc = 0.f; int run = 0;
  for (int n = n0; n < nend; ++n) {
    int b = batch[n];
    if (b != bprev) {
      atomicAdd(&psum[(size_t)bprev * DD + d], acc);
      if (d == 0) atomicAdd(&pcnt[bprev], (float)run);
      acc = 0.f; run = 0; bprev = b;
    }
    acc += fmaf(h[(size_t)n * DD + d], sc, sh);
    ++run;
  }
  atomicAdd(&psum[(size_t)bprev * DD + d], acc);
  if (d == 0) atomicAdd(&pcnt[bprev], (float)run);
}

__global__ __launch_bounds__(256) void head_kernel(
    const float* __restrict__ psum, const float* __restrict__ pcnt,
    const float* __restrict__ pw1, const float* __restrict__ pb1,
    const float* __restrict__ pw2, const float* __restrict__ pb2,
    float* __restrict__ out) {
  __shared__ float row[4][DD], y1[4][DD];
  int tid = threadIdx.x, g = tid >> 6, d = tid & 63;
  int q = blockIdx.x * 4 + g;               // NG % 4 == 0
  float c = fmaxf(pcnt[q], 1.0f);
  row[g][d] = psum[(size_t)q * DD + d] * __builtin_amdgcn_rcpf(c);
  __syncthreads();
  float acc = pb1[d];
#pragma unroll
  for (int k = 0; k < DD; ++k) acc = fmaf(row[g][k], pw1[k * DD + d], acc);
  acc = acc > 0.f ? acc : 0.01f * acc;      // leaky relu
  y1[g][d] = acc;
  __syncthreads();
  float o = pb2[d];
#pragma unroll
  for (int k = 0; k < DD; ++k) o = fmaf(y1[g][k], pw2[k * DD + d], o);
  out[(size_t)q * DD + d] = o;
}

// ---------------------------------------------------------------------------
extern "C" void kernel_launch(void* const* d_in, const int* in_sizes, int n_in,
                              void* d_out, int out_size, void* d_ws, size_t ws_size,
                              hipStream_t stream) {
  const float* x     = (const float*)d_in[0];
  const int*   ei    = (const int*)d_in[1];
  const float* ea    = (const float*)d_in[2];
  const int*   batch = (const int*)d_in[3];
  const float* fw0 = (const float*)d_in[4],  *fb0 = (const float*)d_in[5];
  const float* sw0 = (const float*)d_in[6],  *sb0 = (const float*)d_in[7];
  const float* bng0= (const float*)d_in[8],  *bnb0= (const float*)d_in[9];
  const float* fw1 = (const float*)d_in[10], *fb1 = (const float*)d_in[11];
  const float* sw1 = (const float*)d_in[12], *sb1 = (const float*)d_in[13];
  const float* bng1= (const float*)d_in[14], *bnb1= (const float*)d_in[15];
  const float* pw1 = (const float*)d_in[16], *pb1 = (const float*)d_in[17];
  const float* pw2 = (const float*)d_in[18], *pb2 = (const float*)d_in[19];

  const size_t NND = (size_t)NN * DD;
  float* ws = (float*)d_ws;
  // weight slices (float2 interleaved), per layer
  float2* Wd0 = (float2*)ws;                       // 64x64
  float2* Wsc0 = Wd0 + 64 * DD;
  float2* We0 = Wsc0 + 64 * DD;                    // 16x64
  float2* Wd1 = We0 + ED * DD;
  float2* Wsc1 = Wd1 + 64 * DD;
  float2* We1 = Wsc1 + 64 * DD;
  float* big = (float*)(We1 + ED * DD);
  float2* Dst = (float2*)big;                      // NN*64 float2
  float2* Src = Dst + NND;
  float* h1 = (float*)(Src + NND);
  float* h2 = h1 + NND;
  float* stats0 = h2 + NND;                        // 256
  float* stats1 = stats0 + 256;                    // 256
  float* psum   = stats1 + 256;                    // NG*DD
  float* pcnt   = psum + (size_t)NG * DD;          // NG

  hipMemsetAsync(stats0, 0, (512 + (size_t)NG * DD + NG) * sizeof(float), stream);
  prep_weights<<<36, 256, 0, stream>>>(fw0, sw0, Wd0, Wsc0, We0);
  prep_weights<<<36, 256, 0, stream>>>(fw1, sw1, Wd1, Wsc1, We1);

  // ---- layer 0 ----
  node_transform<0><<<NN / 4, 256, 0, stream>>>(x, nullptr, Wd0, Wsc0, fb0, sb0,
                                                Dst, Src, h1);
  edge_kernel<<<NE / 64, 256, 0, stream>>>(ei, (const float4*)ea, We0, Dst, Src, h1);
  bn_stats<<<128, 256, 0, stream>>>(h1, stats0);
  bn_finalize<<<1, 64, 0, stream>>>(stats0, bng0, bnb0);

  // ---- layer 1 (BN0 affine fused into node transform; h2 = normalized h1) ----
  node_transform<1><<<NN / 4, 256, 0, stream>>>(h1, stats0, Wd1, Wsc1, fb1, sb1,
                                                Dst, Src, h2);
  edge_kernel<<<NE / 64, 256, 0, stream>>>(ei, (const float4*)ea, We1, Dst, Src, h2);
  bn_stats<<<128, 256, 0, stream>>>(h2, stats1);
  bn_finalize<<<1, 64, 0, stream>>>(stats1, bng1, bnb1);

  // ---- pool (BN1 affine fused) + head ----
  pool_bn<<<391, 256, 0, stream>>>(h2, batch, stats1, psum, pcnt);
  head_kernel<<<NG / 4, 256, 0, stream>>>(psum, pcnt, pw1, pb1, pw2, pb2, (float*)d_out);
}

// Round 3
// 721.013 us; speedup vs baseline: 1.4900x; 1.3378x over previous
//
#include <hip/hip_runtime.h>

#define NN 50000      // nodes
#define NE 800000     // edges
#define DD 64         // feature dim
#define ED 16         // edge attr dim
#define NG 5000       // graphs

// ---------------------------------------------------------------------------
// Interleave weights: Wd[k][d]={Wf[k][d],Ws[k][d]} (dst rows 0..63),
// Wsc[k][d] (src rows 64..127), We[k][d] (edge rows 128..143).
__global__ __launch_bounds__(256) void prep_weights(
    const float* __restrict__ fw, const float* __restrict__ sw,
    float2* __restrict__ Wd, float2* __restrict__ Wsc, float2* __restrict__ We) {
  int i = blockIdx.x * 256 + threadIdx.x;   // over 144*64
  if (i >= 144 * 64) return;
  int k = i >> 6, d = i & 63;
  float2 v = make_float2(fw[i], sw[i]);
  if (k < 64)       Wd[k * DD + d] = v;
  else if (k < 128) Wsc[(k - 64) * DD + d] = v;
  else              We[(k - 128) * DD + d] = v;
}

// ---------------------------------------------------------------------------
// CSR construction over dst: histogram -> exclusive scan (3 stages) -> scatter
__global__ __launch_bounds__(256) void k_hist(const int* __restrict__ ei,
                                              int* __restrict__ deg) {
  int e = blockIdx.x * 256 + threadIdx.x;
  if (e < NE) atomicAdd(&deg[ei[NE + e]], 1);
}

__global__ __launch_bounds__(256) void k_scan1(const int* __restrict__ deg,
                                               int* __restrict__ rowptr,
                                               int* __restrict__ partials) {
  __shared__ int sm[256];
  int t = threadIdx.x, i = blockIdx.x * 256 + t;
  int v = (i < NN) ? deg[i] : 0;
  sm[t] = v; __syncthreads();
  for (int off = 1; off < 256; off <<= 1) {
    int x = (t >= off) ? sm[t - off] : 0;
    __syncthreads();
    sm[t] += x;
    __syncthreads();
  }
  if (i < NN) rowptr[i] = sm[t] - v;        // exclusive
  if (t == 255) partials[blockIdx.x] = sm[255];
}

__global__ __launch_bounds__(256) void k_scan2(int* __restrict__ partials,
                                               int* __restrict__ poff, int nparts) {
  __shared__ int sm[256];
  int t = threadIdx.x;
  int v = (t < nparts) ? partials[t] : 0;
  sm[t] = v; __syncthreads();
  for (int off = 1; off < 256; off <<= 1) {
    int x = (t >= off) ? sm[t - off] : 0;
    __syncthreads();
    sm[t] += x;
    __syncthreads();
  }
  poff[t] = sm[t] - v;                      // exclusive
}

__global__ __launch_bounds__(256) void k_scan3(int* __restrict__ rowptr,
                                               const int* __restrict__ poff) {
  int i = blockIdx.x * 256 + threadIdx.x;
  if (i < NN) rowptr[i] += poff[blockIdx.x];
  else if (i == NN) rowptr[NN] = NE;
}

__global__ __launch_bounds__(256) void k_scatter(const int* __restrict__ ei,
                                                 int* __restrict__ cursor,
                                                 int* __restrict__ ssrc,
                                                 int* __restrict__ seid) {
  int e = blockIdx.x * 256 + threadIdx.x;
  if (e >= NE) return;
  int dst = ei[NE + e];
  int pos = atomicAdd(&cursor[dst], 1);
  ssrc[pos] = ei[e];
  seid[pos] = e;
}

// ---------------------------------------------------------------------------
// Node transform, 32 nodes/block, 8 nodes/thread (amortizes weight loads 8x).
// Dst[n][d]={Af,As} (x_i parts + biases), Src[n][d]={Bf,Bs} (x_j parts).
// Also writes hcopy (residual base). BN=1: applies BN affine to input first.
template <int BN>
__global__ __launch_bounds__(256) void node_transform(
    const float* __restrict__ hin, const float* __restrict__ stats,
    const float2* __restrict__ Wd, const float2* __restrict__ Wsc,
    const float* __restrict__ bf, const float* __restrict__ sbv,
    float2* __restrict__ Dst, float2* __restrict__ Src,
    float* __restrict__ hcopy) {
  __shared__ float hrow[32][DD];            // 8 KB
  int tid = threadIdx.x, w = tid >> 6, d = tid & 63;
  int nbase = blockIdx.x * 32;
  // cooperative load of 32 rows (512 float4s), BN affine fused
#pragma unroll
  for (int j = 0; j < 2; ++j) {
    int i4 = tid + j * 256;                 // 0..511
    int node = nbase + (i4 >> 4);
    if (node < NN) {
      int c = (i4 & 15) * 4;
      float4 v = *(const float4*)(hin + (size_t)node * DD + c);
      if (BN) {
        v.x = fmaf(v.x, stats[128 + c + 0], stats[192 + c + 0]);
        v.y = fmaf(v.y, stats[128 + c + 1], stats[192 + c + 1]);
        v.z = fmaf(v.z, stats[128 + c + 2], stats[192 + c + 2]);
        v.w = fmaf(v.w, stats[128 + c + 3], stats[192 + c + 3]);
      }
      *(float4*)(&hrow[i4 >> 4][c]) = v;
      *(float4*)(hcopy + (size_t)node * DD + c) = v;
    }
  }
  __syncthreads();

  float bfd = bf[d], sbd = sbv[d];
  float2 ad[8], as_[8];
#pragma unroll
  for (int i = 0; i < 8; ++i) { ad[i] = make_float2(bfd, sbd); as_[i] = make_float2(0.f, 0.f); }

  for (int kk = 0; kk < 16; ++kk) {
    int k0 = kk * 4;
    float2 wd0 = Wd[(k0 + 0) * DD + d], wd1 = Wd[(k0 + 1) * DD + d];
    float2 wd2 = Wd[(k0 + 2) * DD + d], wd3 = Wd[(k0 + 3) * DD + d];
    float2 ws0 = Wsc[(k0 + 0) * DD + d], ws1 = Wsc[(k0 + 1) * DD + d];
    float2 ws2 = Wsc[(k0 + 2) * DD + d], ws3 = Wsc[(k0 + 3) * DD + d];
#pragma unroll
    for (int i = 0; i < 8; ++i) {
      float4 hv = *(const float4*)(&hrow[w * 8 + i][k0]);
      ad[i].x = fmaf(hv.x, wd0.x, ad[i].x); ad[i].y = fmaf(hv.x, wd0.y, ad[i].y);
      as_[i].x = fmaf(hv.x, ws0.x, as_[i].x); as_[i].y = fmaf(hv.x, ws0.y, as_[i].y);
      ad[i].x = fmaf(hv.y, wd1.x, ad[i].x); ad[i].y = fmaf(hv.y, wd1.y, ad[i].y);
      as_[i].x = fmaf(hv.y, ws1.x, as_[i].x); as_[i].y = fmaf(hv.y, ws1.y, as_[i].y);
      ad[i].x = fmaf(hv.z, wd2.x, ad[i].x); ad[i].y = fmaf(hv.z, wd2.y, ad[i].y);
      as_[i].x = fmaf(hv.z, ws2.x, as_[i].x); as_[i].y = fmaf(hv.z, ws2.y, as_[i].y);
      ad[i].x = fmaf(hv.w, wd3.x, ad[i].x); ad[i].y = fmaf(hv.w, wd3.y, ad[i].y);
      as_[i].x = fmaf(hv.w, ws3.x, as_[i].x); as_[i].y = fmaf(hv.w, ws3.y, as_[i].y);
    }
  }
#pragma unroll
  for (int i = 0; i < 8; ++i) {
    int n = nbase + w * 8 + i;
    if (n < NN) {
      Dst[(size_t)n * DD + d] = ad[i];
      Src[(size_t)n * DD + d] = as_[i];
    }
  }
}

// ---------------------------------------------------------------------------
// Node-centric conv: one wave per dst node, walks CSR edge run, accumulates
// in registers, single non-atomic out[n] += acc. We slice lives in 32 VGPRs.
__global__ __launch_bounds__(256) void conv_nodes(
    const int* __restrict__ rowptr, const int* __restrict__ ssrc,
    const int* __restrict__ seid, const float4* __restrict__ ea4,
    const float2* __restrict__ We,
    const float2* __restrict__ Dst, const float2* __restrict__ Src,
    float* __restrict__ out) {
  int tid = threadIdx.x, w = tid >> 6, d = tid & 63;
  int n = blockIdx.x * 4 + w;               // 12500*4 == NN exactly
  float2 we[16];
#pragma unroll
  for (int k = 0; k < 16; ++k) we[k] = We[k * DD + d];

  float2 a = Dst[(size_t)n * DD + d];
  int beg = rowptr[n], end = rowptr[n + 1];
  float acc = 0.f;
  for (int p = beg; p < end; ++p) {
    int s = ssrc[p];
    int e = seid[p];
    const float4* q = ea4 + (size_t)e * 4;
    float4 q0 = q[0], q1 = q[1], q2 = q[2], q3 = q[3];
    float2 b = Src[(size_t)s * DD + d];
    float zk[16] = {q0.x, q0.y, q0.z, q0.w, q1.x, q1.y, q1.z, q1.w,
                    q2.x, q2.y, q2.z, q2.w, q3.x, q3.y, q3.z, q3.w};
    float cf = a.x + b.x, cs = a.y + b.y;
#pragma unroll
    for (int k = 0; k < 16; ++k) {
      cf = fmaf(zk[k], we[k].x, cf);
      cs = fmaf(zk[k], we[k].y, cs);
    }
    float sig = __builtin_amdgcn_rcpf(1.f + __expf(-cf));
    float sp  = fmaxf(cs, 0.f) + __logf(1.f + __expf(-fabsf(cs)));
    acc = fmaf(sig, sp, acc);
  }
  out[(size_t)n * DD + d] += acc;           // out pre-loaded with residual h
}

// ---------------------------------------------------------------------------
__global__ __launch_bounds__(256) void bn_stats(const float* __restrict__ h,
                                                float* __restrict__ stats) {
  int tid = threadIdx.x;
  int c = (tid & 15) * 4;
  int r0 = blockIdx.x * 16 + (tid >> 4);
  float4 s = make_float4(0, 0, 0, 0), ss = make_float4(0, 0, 0, 0);
  for (int r = r0; r < NN; r += gridDim.x * 16) {
    float4 v = *(const float4*)(h + (size_t)r * DD + c);
    s.x += v.x; s.y += v.y; s.z += v.z; s.w += v.w;
    ss.x += v.x * v.x; ss.y += v.y * v.y; ss.z += v.z * v.z; ss.w += v.w * v.w;
  }
  __shared__ float4 sm[256], sm2[256];
  sm[tid] = s; sm2[tid] = ss;
  __syncthreads();
  for (int str = 128; str >= 16; str >>= 1) {
    if (tid < str) {
      sm[tid].x += sm[tid + str].x; sm[tid].y += sm[tid + str].y;
      sm[tid].z += sm[tid + str].z; sm[tid].w += sm[tid + str].w;
      sm2[tid].x += sm2[tid + str].x; sm2[tid].y += sm2[tid + str].y;
      sm2[tid].z += sm2[tid + str].z; sm2[tid].w += sm2[tid + str].w;
    }
    __syncthreads();
  }
  if (tid < 16) {
    int cc = tid * 4;
    atomicAdd(&stats[cc + 0], sm[tid].x); atomicAdd(&stats[cc + 1], sm[tid].y);
    atomicAdd(&stats[cc + 2], sm[tid].z); atomicAdd(&stats[cc + 3], sm[tid].w);
    atomicAdd(&stats[64 + cc + 0], sm2[tid].x); atomicAdd(&stats[64 + cc + 1], sm2[tid].y);
    atomicAdd(&stats[64 + cc + 2], sm2[tid].z); atomicAdd(&stats[64 + cc + 3], sm2[tid].w);
  }
}

__global__ void bn_finalize(float* __restrict__ stats,
                            const float* __restrict__ gamma,
                            const float* __restrict__ beta) {
  int d = threadIdx.x;  // 64 threads
  const float invN = 1.f / (float)NN;
  float mu  = stats[d] * invN;
  float var = stats[64 + d] * invN - mu * mu;
  float rs  = rsqrtf(var + 1e-5f);
  float sc  = rs * gamma[d];
  stats[128 + d] = sc;
  stats[192 + d] = beta[d] - mu * sc;
}

// ---------------------------------------------------------------------------
__global__ __launch_bounds__(256) void pool_bn(
    const float* __restrict__ h, const int* __restrict__ batch,
    const float* __restrict__ stats,
    float* __restrict__ psum, float* __restrict__ pcnt) {
  int tid = threadIdx.x, g = tid >> 6, d = tid & 63;
  float sc = stats[128 + d], sh = stats[192 + d];
  int n0 = (blockIdx.x * 4 + g) * 32;
  if (n0 >= NN) return;
  int nend = n0 + 32; if (nend > NN) nend = NN;
  int bprev = batch[n0];
  float acc = 0.f; int run = 0;
  for (int n = n0; n < nend; ++n) {
    int b = batch[n];
    if (b != bprev) {
      atomicAdd(&psum[(size_t)bprev * DD + d], acc);
      if (d == 0) atomicAdd(&pcnt[bprev], (float)run);
      acc = 0.f; run = 0; bprev = b;
    }
    acc += fmaf(h[(size_t)n * DD + d], sc, sh);
    ++run;
  }
  atomicAdd(&psum[(size_t)bprev * DD + d], acc);
  if (d == 0) atomicAdd(&pcnt[bprev], (float)run);
}

__global__ __launch_bounds__(256) void head_kernel(
    const float* __restrict__ psum, const float* __restrict__ pcnt,
    const float* __restrict__ pw1, const float* __restrict__ pb1,
    const float* __restrict__ pw2, const float* __restrict__ pb2,
    float* __restrict__ out) {
  __shared__ float row[4][DD], y1[4][DD];
  int tid = threadIdx.x, g = tid >> 6, d = tid & 63;
  int q = blockIdx.x * 4 + g;               // NG % 4 == 0
  float c = fmaxf(pcnt[q], 1.0f);
  row[g][d] = psum[(size_t)q * DD + d] * __builtin_amdgcn_rcpf(c);
  __syncthreads();
  float acc = pb1[d];
#pragma unroll
  for (int k = 0; k < DD; ++k) acc = fmaf(row[g][k], pw1[k * DD + d], acc);
  acc = acc > 0.f ? acc : 0.01f * acc;      // leaky relu
  y1[g][d] = acc;
  __syncthreads();
  float o = pb2[d];
#pragma unroll
  for (int k = 0; k < DD; ++k) o = fmaf(y1[g][k], pw2[k * DD + d], o);
  out[(size_t)q * DD + d] = o;
}

// ---------------------------------------------------------------------------
extern "C" void kernel_launch(void* const* d_in, const int* in_sizes, int n_in,
                              void* d_out, int out_size, void* d_ws, size_t ws_size,
                              hipStream_t stream) {
  const float* x     = (const float*)d_in[0];
  const int*   ei    = (const int*)d_in[1];
  const float* ea    = (const float*)d_in[2];
  const int*   batch = (const int*)d_in[3];
  const float* fw0 = (const float*)d_in[4],  *fb0 = (const float*)d_in[5];
  const float* sw0 = (const float*)d_in[6],  *sb0 = (const float*)d_in[7];
  const float* bng0= (const float*)d_in[8],  *bnb0= (const float*)d_in[9];
  const float* fw1 = (const float*)d_in[10], *fb1 = (const float*)d_in[11];
  const float* sw1 = (const float*)d_in[12], *sb1 = (const float*)d_in[13];
  const float* bng1= (const float*)d_in[14], *bnb1= (const float*)d_in[15];
  const float* pw1 = (const float*)d_in[16], *pb1 = (const float*)d_in[17];
  const float* pw2 = (const float*)d_in[18], *pb2 = (const float*)d_in[19];

  const size_t NND = (size_t)NN * DD;
  // ---- workspace layout (float2 arrays first for 8B alignment) ----
  float2* Wd0  = (float2*)d_ws;                    // 64x64
  float2* Wsc0 = Wd0 + 64 * DD;
  float2* We0  = Wsc0 + 64 * DD;                   // 16x64
  float2* Wd1  = We0 + ED * DD;
  float2* Wsc1 = Wd1 + 64 * DD;
  float2* We1  = Wsc1 + 64 * DD;
  float2* Dst  = We1 + ED * DD;                    // NN*64
  float2* Src  = Dst + NND;
  float*  h1   = (float*)(Src + NND);              // NN*64
  float*  h2   = h1 + NND;
  // zero-init region (one memset): deg | stats0 | stats1 | psum | pcnt
  int*    deg    = (int*)(h2 + NND);               // NN
  float*  stats0 = (float*)(deg + NN);             // 256
  float*  stats1 = stats0 + 256;                   // 256
  float*  psum   = stats1 + 256;                   // NG*DD
  float*  pcnt   = psum + (size_t)NG * DD;         // NG
  // sort scratch
  int* rowptr   = (int*)(pcnt + NG);               // NN+1
  int* cursor   = rowptr + NN + 1;                 // NN
  int* partials = cursor + NN;                     // 256
  int* poff     = partials + 256;                  // 256
  int* ssrc     = poff + 256;                      // NE
  int* seid     = ssrc + NE;                       // NE

  const int NB_NODE = (NN + 255) / 256;            // 196

  hipMemsetAsync(deg, 0,
                 ((size_t)NN + 512 + (size_t)NG * DD + NG) * sizeof(float), stream);
  prep_weights<<<36, 256, 0, stream>>>(fw0, sw0, Wd0, Wsc0, We0);
  prep_weights<<<36, 256, 0, stream>>>(fw1, sw1, Wd1, Wsc1, We1);

  // ---- CSR build (once, reused by both layers) ----
  k_hist<<<(NE + 255) / 256, 256, 0, stream>>>(ei, deg);
  k_scan1<<<NB_NODE, 256, 0, stream>>>(deg, rowptr, partials);
  k_scan2<<<1, 256, 0, stream>>>(partials, poff, NB_NODE);
  k_scan3<<<NB_NODE + 1, 256, 0, stream>>>(rowptr, poff);
  hipMemcpyAsync(cursor, rowptr, NN * sizeof(int), hipMemcpyDeviceToDevice, stream);
  k_scatter<<<(NE + 255) / 256, 256, 0, stream>>>(ei, cursor, ssrc, seid);

  // ---- layer 0 ----
  node_transform<0><<<(NN + 31) / 32, 256, 0, stream>>>(x, nullptr, Wd0, Wsc0,
                                                        fb0, sb0, Dst, Src, h1);
  conv_nodes<<<NN / 4, 256, 0, stream>>>(rowptr, ssrc, seid, (const float4*)ea,
                                         We0, Dst, Src, h1);
  bn_stats<<<128, 256, 0, stream>>>(h1, stats0);
  bn_finalize<<<1, 64, 0, stream>>>(stats0, bng0, bnb0);

  // ---- layer 1 (BN0 affine fused into node transform) ----
  node_transform<1><<<(NN + 31) / 32, 256, 0, stream>>>(h1, stats0, Wd1, Wsc1,
                                                        fb1, sb1, Dst, Src, h2);
  conv_nodes<<<NN / 4, 256, 0, stream>>>(rowptr, ssrc, seid, (const float4*)ea,
                                         We1, Dst, Src, h2);
  bn_stats<<<128, 256, 0, stream>>>(h2, stats1);
  bn_finalize<<<1, 64, 0, stream>>>(stats1, bng1, bnb1);

  // ---- pool (BN1 affine fused) + head ----
  pool_bn<<<391, 256, 0, stream>>>(h2, batch, stats1, psum, pcnt);
  head_kernel<<<NG / 4, 256, 0, stream>>>(psum, pcnt, pw1, pb1, pw2, pb2, (float*)d_out);
}

// Round 4
// 570.554 us; speedup vs baseline: 1.8830x; 1.2637x over previous
//
#include <hip/hip_runtime.h>

#define NN 50000      // nodes
#define NE 800000     // edges
#define DD 64         // feature dim
#define ED 16         // edge attr dim
#define NG 5000       // graphs
#define SS 16         // sorted-edge strip per wave

// ---------------------------------------------------------------------------
// Interleave weights for both layers in one launch:
// Wd[k][d]={Wf[k][d],Ws[k][d]} (dst rows 0..63), Wsc (src rows 64..127),
// We (edge rows 128..143).
__global__ __launch_bounds__(256) void prep_weights(
    const float* __restrict__ fw0, const float* __restrict__ sw0,
    const float* __restrict__ fw1, const float* __restrict__ sw1,
    float2* __restrict__ Wd0, float2* __restrict__ Wsc0, float2* __restrict__ We0,
    float2* __restrict__ Wd1, float2* __restrict__ Wsc1, float2* __restrict__ We1) {
  int i = blockIdx.x * 256 + threadIdx.x;   // over 2*144*64
  if (i >= 2 * 144 * 64) return;
  int layer = i >= 144 * 64;
  int j = i - layer * 144 * 64;
  int k = j >> 6, d = j & 63;
  const float* fw = layer ? fw1 : fw0;
  const float* sw = layer ? sw1 : sw0;
  float2 v = make_float2(fw[j], sw[j]);
  float2* Wd = layer ? Wd1 : Wd0;
  float2* Wsc = layer ? Wsc1 : Wsc0;
  float2* We = layer ? We1 : We0;
  if (k < 64)       Wd[k * DD + d] = v;
  else if (k < 128) Wsc[(k - 64) * DD + d] = v;
  else              We[(k - 128) * DD + d] = v;
}

// ---------------------------------------------------------------------------
// CSR construction over dst: histogram -> exclusive scan -> scatter (with
// edge-attr gather into sorted order).
__global__ __launch_bounds__(256) void k_hist(const int* __restrict__ ei,
                                              int* __restrict__ deg) {
  int e = blockIdx.x * 256 + threadIdx.x;
  if (e < NE) atomicAdd(&deg[ei[NE + e]], 1);
}

__global__ __launch_bounds__(256) void k_scan1(const int* __restrict__ deg,
                                               int* __restrict__ rowptr,
                                               int* __restrict__ partials) {
  __shared__ int sm[256];
  int t = threadIdx.x, i = blockIdx.x * 256 + t;
  int v = (i < NN) ? deg[i] : 0;
  sm[t] = v; __syncthreads();
  for (int off = 1; off < 256; off <<= 1) {
    int x = (t >= off) ? sm[t - off] : 0;
    __syncthreads();
    sm[t] += x;
    __syncthreads();
  }
  if (i < NN) rowptr[i] = sm[t] - v;        // exclusive
  if (t == 255) partials[blockIdx.x] = sm[255];
}

__global__ __launch_bounds__(256) void k_scan2(int* __restrict__ partials,
                                               int* __restrict__ poff, int nparts) {
  __shared__ int sm[256];
  int t = threadIdx.x;
  int v = (t < nparts) ? partials[t] : 0;
  sm[t] = v; __syncthreads();
  for (int off = 1; off < 256; off <<= 1) {
    int x = (t >= off) ? sm[t - off] : 0;
    __syncthreads();
    sm[t] += x;
    __syncthreads();
  }
  poff[t] = sm[t] - v;                      // exclusive
}

__global__ __launch_bounds__(256) void k_scan3(int* __restrict__ rowptr,
                                               int* __restrict__ cursor,
                                               const int* __restrict__ poff) {
  int i = blockIdx.x * 256 + threadIdx.x;
  if (i < NN) {
    int v = rowptr[i] + poff[blockIdx.x];
    rowptr[i] = v;
    cursor[i] = v;
  } else if (i == NN) {
    rowptr[NN] = NE;
  }
}

__global__ __launch_bounds__(256) void k_scatter(const int* __restrict__ ei,
                                                 const float4* __restrict__ ea4,
                                                 int* __restrict__ cursor,
                                                 int* __restrict__ ssrc,
                                                 int* __restrict__ sdst,
                                                 float4* __restrict__ sea4) {
  int e = blockIdx.x * 256 + threadIdx.x;
  if (e >= NE) return;
  int dst = ei[NE + e];
  int pos = atomicAdd(&cursor[dst], 1);
  ssrc[pos] = ei[e];
  sdst[pos] = dst;
  const float4* q = ea4 + (size_t)e * 4;
  float4 a0 = q[0], a1 = q[1], a2 = q[2], a3 = q[3];
  float4* o = sea4 + (size_t)pos * 4;
  o[0] = a0; o[1] = a1; o[2] = a2; o[3] = a3;
}

// ---------------------------------------------------------------------------
// Node transform, 32 nodes/block, 8 nodes/thread. BN=1: fuses BN finalize
// (raw moments -> scale/shift) + affine into the input load.
template <int BN>
__global__ __launch_bounds__(256) void node_transform(
    const float* __restrict__ hin, const float* __restrict__ stats,
    const float* __restrict__ gamma, const float* __restrict__ beta,
    const float2* __restrict__ Wd, const float2* __restrict__ Wsc,
    const float* __restrict__ bf, const float* __restrict__ sbv,
    float2* __restrict__ Dst, float2* __restrict__ Src,
    float* __restrict__ hcopy) {
  __shared__ float hrow[32][DD];            // 8 KB
  int tid = threadIdx.x, w = tid >> 6, d = tid & 63;
  int nbase = blockIdx.x * 32;
  const float invN = 1.f / (float)NN;
#pragma unroll
  for (int j = 0; j < 2; ++j) {
    int i4 = tid + j * 256;                 // 0..511
    int node = nbase + (i4 >> 4);
    if (node < NN) {
      int c = (i4 & 15) * 4;
      float4 v = *(const float4*)(hin + (size_t)node * DD + c);
      if (BN) {
        float mu0 = stats[c + 0] * invN, va0 = stats[64 + c + 0] * invN - mu0 * mu0;
        float mu1 = stats[c + 1] * invN, va1 = stats[64 + c + 1] * invN - mu1 * mu1;
        float mu2 = stats[c + 2] * invN, va2 = stats[64 + c + 2] * invN - mu2 * mu2;
        float mu3 = stats[c + 3] * invN, va3 = stats[64 + c + 3] * invN - mu3 * mu3;
        float sc0 = rsqrtf(va0 + 1e-5f) * gamma[c + 0];
        float sc1 = rsqrtf(va1 + 1e-5f) * gamma[c + 1];
        float sc2 = rsqrtf(va2 + 1e-5f) * gamma[c + 2];
        float sc3 = rsqrtf(va3 + 1e-5f) * gamma[c + 3];
        v.x = fmaf(v.x, sc0, beta[c + 0] - mu0 * sc0);
        v.y = fmaf(v.y, sc1, beta[c + 1] - mu1 * sc1);
        v.z = fmaf(v.z, sc2, beta[c + 2] - mu2 * sc2);
        v.w = fmaf(v.w, sc3, beta[c + 3] - mu3 * sc3);
      }
      *(float4*)(&hrow[i4 >> 4][c]) = v;
      *(float4*)(hcopy + (size_t)node * DD + c) = v;
    }
  }
  __syncthreads();

  float bfd = bf[d], sbd = sbv[d];
  float2 ad[8], as_[8];
#pragma unroll
  for (int i = 0; i < 8; ++i) { ad[i] = make_float2(bfd, sbd); as_[i] = make_float2(0.f, 0.f); }

  for (int kk = 0; kk < 16; ++kk) {
    int k0 = kk * 4;
    float2 wd0 = Wd[(k0 + 0) * DD + d], wd1 = Wd[(k0 + 1) * DD + d];
    float2 wd2 = Wd[(k0 + 2) * DD + d], wd3 = Wd[(k0 + 3) * DD + d];
    float2 ws0 = Wsc[(k0 + 0) * DD + d], ws1 = Wsc[(k0 + 1) * DD + d];
    float2 ws2 = Wsc[(k0 + 2) * DD + d], ws3 = Wsc[(k0 + 3) * DD + d];
#pragma unroll
    for (int i = 0; i < 8; ++i) {
      float4 hv = *(const float4*)(&hrow[w * 8 + i][k0]);
      ad[i].x = fmaf(hv.x, wd0.x, ad[i].x); ad[i].y = fmaf(hv.x, wd0.y, ad[i].y);
      as_[i].x = fmaf(hv.x, ws0.x, as_[i].x); as_[i].y = fmaf(hv.x, ws0.y, as_[i].y);
      ad[i].x = fmaf(hv.y, wd1.x, ad[i].x); ad[i].y = fmaf(hv.y, wd1.y, ad[i].y);
      as_[i].x = fmaf(hv.y, ws1.x, as_[i].x); as_[i].y = fmaf(hv.y, ws1.y, as_[i].y);
      ad[i].x = fmaf(hv.z, wd2.x, ad[i].x); ad[i].y = fmaf(hv.z, wd2.y, ad[i].y);
      as_[i].x = fmaf(hv.z, ws2.x, as_[i].x); as_[i].y = fmaf(hv.z, ws2.y, as_[i].y);
      ad[i].x = fmaf(hv.w, wd3.x, ad[i].x); ad[i].y = fmaf(hv.w, wd3.y, ad[i].y);
      as_[i].x = fmaf(hv.w, ws3.x, as_[i].x); as_[i].y = fmaf(hv.w, ws3.y, as_[i].y);
    }
  }
#pragma unroll
  for (int i = 0; i < 8; ++i) {
    int n = nbase + w * 8 + i;
    if (n < NN) {
      Dst[(size_t)n * DD + d] = ad[i];
      Src[(size_t)n * DD + d] = as_[i];
    }
  }
}

// ---------------------------------------------------------------------------
// Strip-parallel conv over sorted edges: one wave per SS edges. All SS src
// gathers issued up-front (MLP), run-length accumulate over sorted dst,
// atomic flush at run boundaries only. ea staged in LDS (coalesced).
__global__ __launch_bounds__(256, 4) void conv_strip(
    const int* __restrict__ ssrc, const int* __restrict__ sdst,
    const float4* __restrict__ sea4, const float2* __restrict__ We,
    const float2* __restrict__ Dst, const float2* __restrict__ Src,
    float* __restrict__ out) {
  __shared__ float4 sEA[4][SS * 4];         // 16 edges * 64B per wave
  __shared__ int sid[4][2 * SS];
  int tid = threadIdx.x, w = tid >> 6, d = tid & 63;
  int strip = blockIdx.x * 4 + w;           // NE/SS strips exactly
  size_t base = (size_t)strip * SS;

  sEA[w][d] = sea4[base * 4 + d];           // 64 float4 = strip's ea
  if (d < 2 * SS) sid[w][d] = (d < SS) ? ssrc[base + d] : sdst[base + d - SS];
  __syncthreads();

  float2 we[16];
#pragma unroll
  for (int k = 0; k < 16; ++k) we[k] = We[k * DD + d];

  // prefetch all SS src rows (independent loads in flight)
  float2 b[SS];
#pragma unroll
  for (int i = 0; i < SS; ++i) b[i] = Src[(size_t)sid[w][i] * DD + d];

  int curdst = sid[w][SS];
  float2 a = Dst[(size_t)curdst * DD + d];
  float acc = 0.f;
#pragma unroll
  for (int i = 0; i < SS; ++i) {
    int dstn = sid[w][SS + i];
    if (dstn != curdst) {                   // wave-uniform branch
      atomicAdd(&out[(size_t)curdst * DD + d], acc);
      acc = 0.f;
      curdst = dstn;
      a = Dst[(size_t)curdst * DD + d];
    }
    float cf = a.x + b[i].x, cs = a.y + b[i].y;
#pragma unroll
    for (int k = 0; k < 4; ++k) {
      float4 z = sEA[w][i * 4 + k];
      cf = fmaf(z.x, we[4 * k + 0].x, cf); cs = fmaf(z.x, we[4 * k + 0].y, cs);
      cf = fmaf(z.y, we[4 * k + 1].x, cf); cs = fmaf(z.y, we[4 * k + 1].y, cs);
      cf = fmaf(z.z, we[4 * k + 2].x, cf); cs = fmaf(z.z, we[4 * k + 2].y, cs);
      cf = fmaf(z.w, we[4 * k + 3].x, cf); cs = fmaf(z.w, we[4 * k + 3].y, cs);
    }
    float sig = __builtin_amdgcn_rcpf(1.f + __expf(-cf));
    float sp  = fmaxf(cs, 0.f) + __logf(1.f + __expf(-fabsf(cs)));
    acc = fmaf(sig, sp, acc);
  }
  atomicAdd(&out[(size_t)curdst * DD + d], acc);
}

// ---------------------------------------------------------------------------
__global__ __launch_bounds__(256) void bn_stats(const float* __restrict__ h,
                                                float* __restrict__ stats) {
  int tid = threadIdx.x;
  int c = (tid & 15) * 4;
  int r0 = blockIdx.x * 16 + (tid >> 4);
  float4 s = make_float4(0, 0, 0, 0), ss = make_float4(0, 0, 0, 0);
  for (int r = r0; r < NN; r += gridDim.x * 16) {
    float4 v = *(const float4*)(h + (size_t)r * DD + c);
    s.x += v.x; s.y += v.y; s.z += v.z; s.w += v.w;
    ss.x += v.x * v.x; ss.y += v.y * v.y; ss.z += v.z * v.z; ss.w += v.w * v.w;
  }
  __shared__ float4 sm[256], sm2[256];
  sm[tid] = s; sm2[tid] = ss;
  __syncthreads();
  for (int str = 128; str >= 16; str >>= 1) {
    if (tid < str) {
      sm[tid].x += sm[tid + str].x; sm[tid].y += sm[tid + str].y;
      sm[tid].z += sm[tid + str].z; sm[tid].w += sm[tid + str].w;
      sm2[tid].x += sm2[tid + str].x; sm2[tid].y += sm2[tid + str].y;
      sm2[tid].z += sm2[tid + str].z; sm2[tid].w += sm2[tid + str].w;
    }
    __syncthreads();
  }
  if (tid < 16) {
    int cc = tid * 4;
    atomicAdd(&stats[cc + 0], sm[tid].x); atomicAdd(&stats[cc + 1], sm[tid].y);
    atomicAdd(&stats[cc + 2], sm[tid].z); atomicAdd(&stats[cc + 3], sm[tid].w);
    atomicAdd(&stats[64 + cc + 0], sm2[tid].x); atomicAdd(&stats[64 + cc + 1], sm2[tid].y);
    atomicAdd(&stats[64 + cc + 2], sm2[tid].z); atomicAdd(&stats[64 + cc + 3], sm2[tid].w);
  }
}

// ---------------------------------------------------------------------------
// Pool with fused BN1 finalize+affine; run-length accumulate on sorted batch.
__global__ __launch_bounds__(256) void pool_bn(
    const float* __restrict__ h, const int* __restrict__ batch,
    const float* __restrict__ stats,
    const float* __restrict__ gamma, const float* __restrict__ beta,
    float* __restrict__ psum, float* __restrict__ pcnt) {
  int tid = threadIdx.x, g = tid >> 6, d = tid & 63;
  const float invN = 1.f / (float)NN;
  float mu = stats[d] * invN;
  float var = stats[64 + d] * invN - mu * mu;
  float sc = rsqrtf(var + 1e-5f) * gamma[d];
  float sh = beta[d] - mu * sc;
  int n0 = (blockIdx.x * 4 + g) * 32;
  if (n0 >= NN) return;
  int nend = n0 + 32; if (nend > NN) nend = NN;
  int bprev = batch[n0];
  float acc = 0.f; int run = 0;
  for (int n = n0; n < nend; ++n) {
    int b = batch[n];
    if (b != bprev) {
      atomicAdd(&psum[(size_t)bprev * DD + d], acc);
      if (d == 0) atomicAdd(&pcnt[bprev], (float)run);
      acc = 0.f; run = 0; bprev = b;
    }
    acc += fmaf(h[(size_t)n * DD + d], sc, sh);
    ++run;
  }
  atomicAdd(&psum[(size_t)bprev * DD + d], acc);
  if (d == 0) atomicAdd(&pcnt[bprev], (float)run);
}

__global__ __launch_bounds__(256) void head_kernel(
    const float* __restrict__ psum, const float* __restrict__ pcnt,
    const float* __restrict__ pw1, const float* __restrict__ pb1,
    const float* __restrict__ pw2, const float* __restrict__ pb2,
    float* __restrict__ out) {
  __shared__ float row[4][DD], y1[4][DD];
  int tid = threadIdx.x, g = tid >> 6, d = tid & 63;
  int q = blockIdx.x * 4 + g;               // NG % 4 == 0
  float c = fmaxf(pcnt[q], 1.0f);
  row[g][d] = psum[(size_t)q * DD + d] * __builtin_amdgcn_rcpf(c);
  __syncthreads();
  float acc = pb1[d];
#pragma unroll
  for (int k = 0; k < DD; ++k) acc = fmaf(row[g][k], pw1[k * DD + d], acc);
  acc = acc > 0.f ? acc : 0.01f * acc;      // leaky relu
  y1[g][d] = acc;
  __syncthreads();
  float o = pb2[d];
#pragma unroll
  for (int k = 0; k < DD; ++k) o = fmaf(y1[g][k], pw2[k * DD + d], o);
  out[(size_t)q * DD + d] = o;
}

// ---------------------------------------------------------------------------
extern "C" void kernel_launch(void* const* d_in, const int* in_sizes, int n_in,
                              void* d_out, int out_size, void* d_ws, size_t ws_size,
                              hipStream_t stream) {
  const float* x     = (const float*)d_in[0];
  const int*   ei    = (const int*)d_in[1];
  const float* ea    = (const float*)d_in[2];
  const int*   batch = (const int*)d_in[3];
  const float* fw0 = (const float*)d_in[4],  *fb0 = (const float*)d_in[5];
  const float* sw0 = (const float*)d_in[6],  *sb0 = (const float*)d_in[7];
  const float* bng0= (const float*)d_in[8],  *bnb0= (const float*)d_in[9];
  const float* fw1 = (const float*)d_in[10], *fb1 = (const float*)d_in[11];
  const float* sw1 = (const float*)d_in[12], *sb1 = (const float*)d_in[13];
  const float* bng1= (const float*)d_in[14], *bnb1= (const float*)d_in[15];
  const float* pw1 = (const float*)d_in[16], *pb1 = (const float*)d_in[17];
  const float* pw2 = (const float*)d_in[18], *pb2 = (const float*)d_in[19];

  const size_t NND = (size_t)NN * DD;
  // ---- workspace layout (16B-aligned chunks first) ----
  float4* sea4 = (float4*)d_ws;                    // NE*4 float4 (51.2MB)
  float2* Wd0  = (float2*)(sea4 + (size_t)NE * 4); // 64x64
  float2* Wsc0 = Wd0 + 64 * DD;
  float2* We0  = Wsc0 + 64 * DD;                   // 16x64
  float2* Wd1  = We0 + ED * DD;
  float2* Wsc1 = Wd1 + 64 * DD;
  float2* We1  = Wsc1 + 64 * DD;
  float2* Dst  = We1 + ED * DD;                    // NN*64
  float2* Src  = Dst + NND;
  float*  h1   = (float*)(Src + NND);              // NN*64
  float*  h2   = h1 + NND;
  // zero-init region (one memset): deg | stats0 | stats1 | psum | pcnt
  int*    deg    = (int*)(h2 + NND);               // NN
  float*  stats0 = (float*)(deg + NN);             // 256
  float*  stats1 = stats0 + 256;                   // 256
  float*  psum   = stats1 + 256;                   // NG*DD
  float*  pcnt   = psum + (size_t)NG * DD;         // NG
  // sort scratch
  int* rowptr   = (int*)(pcnt + NG);               // NN+1
  int* cursor   = rowptr + NN + 1;                 // NN
  int* partials = cursor + NN;                     // 256
  int* poff     = partials + 256;                  // 256
  int* ssrc     = poff + 256;                      // NE
  int* sdst     = ssrc + NE;                       // NE

  const int NB_NODE = (NN + 255) / 256;            // 196

  hipMemsetAsync(deg, 0,
                 ((size_t)NN + 512 + (size_t)NG * DD + NG) * sizeof(float), stream);
  prep_weights<<<72, 256, 0, stream>>>(fw0, sw0, fw1, sw1,
                                       Wd0, Wsc0, We0, Wd1, Wsc1, We1);

  // ---- CSR build (once, reused by both layers) ----
  k_hist<<<(NE + 255) / 256, 256, 0, stream>>>(ei, deg);
  k_scan1<<<NB_NODE, 256, 0, stream>>>(deg, rowptr, partials);
  k_scan2<<<1, 256, 0, stream>>>(partials, poff, NB_NODE);
  k_scan3<<<(NN + 256) / 256, 256, 0, stream>>>(rowptr, cursor, poff);
  k_scatter<<<(NE + 255) / 256, 256, 0, stream>>>(ei, (const float4*)ea, cursor,
                                                  ssrc, sdst, sea4);

  // ---- layer 0 ----
  node_transform<0><<<(NN + 31) / 32, 256, 0, stream>>>(
      x, nullptr, nullptr, nullptr, Wd0, Wsc0, fb0, sb0, Dst, Src, h1);
  conv_strip<<<NE / SS / 4, 256, 0, stream>>>(ssrc, sdst, sea4, We0, Dst, Src, h1);
  bn_stats<<<128, 256, 0, stream>>>(h1, stats0);

  // ---- layer 1 (BN0 finalize+affine fused into node transform) ----
  node_transform<1><<<(NN + 31) / 32, 256, 0, stream>>>(
      h1, stats0, bng0, bnb0, Wd1, Wsc1, fb1, sb1, Dst, Src, h2);
  conv_strip<<<NE / SS / 4, 256, 0, stream>>>(ssrc, sdst, sea4, We1, Dst, Src, h2);
  bn_stats<<<128, 256, 0, stream>>>(h2, stats1);

  // ---- pool (BN1 finalize+affine fused) + head ----
  pool_bn<<<391, 256, 0, stream>>>(h2, batch, stats1, bng1, bnb1, psum, pcnt);
  head_kernel<<<NG / 4, 256, 0, stream>>>(psum, pcnt, pw1, pb1, pw2, pb2, (float*)d_out);
}